// Round 12
// baseline (235.600 us; speedup 1.0000x reference)
//
#include <hip/hip_runtime.h>
#include <hip/hip_bf16.h>

typedef __hip_bfloat16 bf16;

#define N_NODES 16384
#define D_FIL 512
#define D_IN 532
#define D_MODEL 1024
#define NHEAD 16
#define D_KEY 64
#define DFF 4096
#define NTREE 128
#define MEM_SLOTS 8
#define NODES_PER_TREE 128
#define EPS 1e-5f
#define XSE 544          // xs row stride in elements (bf16), 16B-aligned rows
#define XSU 272          // xs row stride in uints
#define CSTR 32          // counts stride in ints: 1 counter per 128B cache line
#define BSTR 40          // MFMA-GEMM B-tile LDS row stride in bf16 (80 B)

typedef float f32x4 __attribute__((ext_vector_type(4)));
typedef short s16x8 __attribute__((ext_vector_type(8)));

union PackU { uint4 u; s16x8 s; };

__device__ inline float gelu_exact(float x) {
    return 0.5f * x * (1.0f + erff(x * 0.7071067811865476f));
}

// block-wide (512 threads, 8 waves) simultaneous sum of two values
__device__ inline void blockReduceSum2_512(float& a, float& b, float* sm) {
    int tid = threadIdx.x;
    int lane = tid & 63, wid = tid >> 6;
#pragma unroll
    for (int off = 32; off > 0; off >>= 1) {
        a += __shfl_down(a, off, 64);
        b += __shfl_down(b, off, 64);
    }
    if (lane == 0) { sm[wid] = a; sm[8 + wid] = b; }
    __syncthreads();
    if (tid == 0) {
        float s0 = 0.f, s1 = 0.f;
#pragma unroll
        for (int i = 0; i < 8; ++i) { s0 += sm[i]; s1 += sm[8 + i]; }
        sm[16] = s0; sm[17] = s1;
    }
    __syncthreads();
    a = sm[16]; b = sm[17];
}

// ---------------- fused prep: wq (blocks 0..15) + Wv transpose (16..559) + node prep (560..4655) ----
__global__ __launch_bounds__(256) void prep_kernel(
        const float* __restrict__ values, const int* __restrict__ role,
        const int* __restrict__ bidx, const int* __restrict__ midx,
        const float* __restrict__ g_fil, const float* __restrict__ b_fil,
        const float* __restrict__ g_mha, const float* __restrict__ b_mha,
        bf16* __restrict__ xs, int* __restrict__ counts,
        const float* __restrict__ q, const float* __restrict__ Wk,
        unsigned* __restrict__ wqb,
        const float* __restrict__ Wv, float* __restrict__ wvt) {
    int b = blockIdx.x;
    int tid = threadIdx.x;

    if (b < 16) {
        // ---------------- wq branch ----------------
        int h = b;
        __shared__ float qs[64];
        if (tid < 64) qs[tid] = q[h * 64 + tid];
        __syncthreads();
        for (int p = tid; p < XSU; p += 256) {
            unsigned out = 0u;
            if (p < 266) {
                float a0 = 0.f, a1 = 0.f;
                int j0 = 2 * p;
#pragma unroll 8
                for (int d = 0; d < 64; ++d) {
                    const float* wr = Wk + (size_t)(h * 64 + d) * D_IN;
                    a0 += qs[d] * wr[j0];
                    a1 += qs[d] * wr[j0 + 1];
                }
                unsigned u0 = (unsigned)__bfloat16_as_ushort(__float2bfloat16(a0));
                unsigned u1 = (unsigned)__bfloat16_as_ushort(__float2bfloat16(a1));
                out = (u1 << 16) | u0;
            }
            wqb[h * XSU + p] = out;
        }
        return;
    }

    if (b < 560) {
        // ---------------- Wv transpose branch ----------------
        __shared__ float tile[32][33];
        int vb = b - 16;
        int c0 = (vb & 31) * 32, j0 = (vb >> 5) * 32;
        int tx = tid & 31, ty = tid >> 5;   // 32 x 8
#pragma unroll
        for (int r = 0; r < 4; ++r) {
            int cc = ty + r * 8;
            int j = j0 + tx;
            tile[cc][tx] = (j < D_IN) ? Wv[(size_t)(c0 + cc) * D_IN + j] : 0.f;
        }
        __syncthreads();
#pragma unroll
        for (int r = 0; r < 4; ++r) {
            int j = j0 + ty + r * 8;
            if (j < D_IN) wvt[(size_t)j * D_MODEL + c0 + tx] = tile[tx][ty + r * 8];
        }
        return;
    }

    // ---------------- node prep branch: wave-per-node ----------------
    int wave = tid >> 6;
    int l = tid & 63;
    int n = (b - 560) * 4 + wave;

    // issue the 2KB value load FIRST — nothing downstream of the atomic gates it
    const float4* vp = (const float4*)(values + (size_t)n * D_FIL + l * 8);
    float4 v0 = vp[0], v1 = vp[1];

    // issue the atomic early (lane 0 only); result consumed only at the store
    int row = 0;
    if (l == 0) {
        int slot = bidx[n] * MEM_SLOTS + midx[n];
        int pos = atomicAdd(&counts[slot * CSTR], 1);
        row = slot * NODES_PER_TREE + pos;
    }

    // ---- LN1 over 512 ----
    float s = v0.x + v0.y + v0.z + v0.w + v1.x + v1.y + v1.z + v1.w;
    float ss = v0.x * v0.x + v0.y * v0.y + v0.z * v0.z + v0.w * v0.w
             + v1.x * v1.x + v1.y * v1.y + v1.z * v1.z + v1.w * v1.w;
#pragma unroll
    for (int m = 1; m < 64; m <<= 1) {
        s += __shfl_xor(s, m, 64);
        ss += __shfl_xor(ss, m, 64);
    }
    float mu = s * (1.f / D_FIL);
    float var = ss * (1.f / D_FIL) - mu * mu;
    float rs = rsqrtf(var + EPS);

    const float4* gf = (const float4*)(g_fil + l * 8);
    const float4* bf = (const float4*)(b_fil + l * 8);
    float4 gf0 = gf[0], gf1 = gf[1], bf0 = bf[0], bf1 = bf[1];
    float y[8];
    y[0] = (v0.x - mu) * rs * gf0.x + bf0.x;
    y[1] = (v0.y - mu) * rs * gf0.y + bf0.y;
    y[2] = (v0.z - mu) * rs * gf0.z + bf0.z;
    y[3] = (v0.w - mu) * rs * gf0.w + bf0.w;
    y[4] = (v1.x - mu) * rs * gf1.x + bf1.x;
    y[5] = (v1.y - mu) * rs * gf1.y + bf1.y;
    y[6] = (v1.z - mu) * rs * gf1.z + bf1.z;
    y[7] = (v1.w - mu) * rs * gf1.w + bf1.w;

    // ---- tpd analytic stats ----
    int r = role[n];                 // r >= 1
    int cm = 31 - __clz(r);          // highest set bit, 0..19
    float s_t = 2.f * (float)(__popc(r) - 1) - (float)cm;
    float ss_t = (float)cm;

    // ---- LN2 over 532 ----
    float s2 = y[0] + y[1] + y[2] + y[3] + y[4] + y[5] + y[6] + y[7];
    float ss2 = y[0] * y[0] + y[1] * y[1] + y[2] * y[2] + y[3] * y[3]
              + y[4] * y[4] + y[5] * y[5] + y[6] * y[6] + y[7] * y[7];
#pragma unroll
    for (int m = 1; m < 64; m <<= 1) {
        s2 += __shfl_xor(s2, m, 64);
        ss2 += __shfl_xor(ss2, m, 64);
    }
    s2 += s_t; ss2 += ss_t;
    float mu2 = s2 * (1.f / D_IN);
    float var2 = ss2 * (1.f / D_IN) - mu2 * mu2;
    float rs2 = rsqrtf(var2 + EPS);

    const float4* gm = (const float4*)(g_mha + l * 8);
    const float4* bm = (const float4*)(b_mha + l * 8);
    float4 gm0 = gm[0], gm1 = gm[1], bm0 = bm[0], bm1 = bm[1];
    float x[8];
    x[0] = (y[0] - mu2) * rs2 * gm0.x + bm0.x;
    x[1] = (y[1] - mu2) * rs2 * gm0.y + bm0.y;
    x[2] = (y[2] - mu2) * rs2 * gm0.z + bm0.z;
    x[3] = (y[3] - mu2) * rs2 * gm0.w + bm0.w;
    x[4] = (y[4] - mu2) * rs2 * gm1.x + bm1.x;
    x[5] = (y[5] - mu2) * rs2 * gm1.y + bm1.y;
    x[6] = (y[6] - mu2) * rs2 * gm1.z + bm1.z;
    x[7] = (y[7] - mu2) * rs2 * gm1.w + bm1.w;

    // broadcast row AFTER the compute so the atomic round-trip hid under LN1/LN2
    row = __shfl(row, 0, 64);

    // one uint4 store: 8 bf16 = 16 B, rows 16B-aligned (stride 1088 B)
    {
        unsigned us[8];
#pragma unroll
        for (int k = 0; k < 8; ++k)
            us[k] = (unsigned)__bfloat16_as_ushort(__float2bfloat16(x[k]));
        uint4 pk = make_uint4((us[1] << 16) | us[0], (us[3] << 16) | us[2],
                              (us[5] << 16) | us[4], (us[7] << 16) | us[6]);
        *(uint4*)((char*)xs + (size_t)row * (XSE * 2) + 16 * l) = pk;
    }

    // tail j = 512..531, zero-pad 532..543
    if (l < 20) {
        int bit = (r >> l) & 1;
        float tpd = (l < cm) ? (bit ? 1.f : -1.f) : 0.f;
        float x2 = (tpd - mu2) * rs2 * g_mha[512 + l] + b_mha[512 + l];
        xs[(size_t)row * XSE + 512 + l] = __float2bfloat16(x2);
    } else if (l < 26) {
        ((unsigned*)xs)[(size_t)row * XSU + 266 + (l - 20)] = 0u;
    }
}

// ------- fused qkm + attention (R9-exact body: uint2 qkm for max MLP) + XCD swizzle -------
// flat grid 512: xcd = f&7, hg = (f>>3)&3, t = (f>>5)*8 + xcd  (bijective).
// A tree's 4 head-group blocks share f&7 -> same XCD -> xs slab HBM-fetched once.
__global__ __launch_bounds__(256) void attn_fused_kernel(const unsigned* __restrict__ xsu,
                                                         const unsigned* __restrict__ wqb,
                                                         const float* __restrict__ wvt,
                                                         float* __restrict__ attn_out) {
    int f = blockIdx.x;
    int xcd = f & 7;
    int hg = (f >> 3) & 3;
    int t = (f >> 5) * 8 + xcd;
    int tid = threadIdx.x;
    __shared__ __align__(16) float a4[NODES_PER_TREE * 4];   // [i*4 + hh]
    __shared__ __align__(16) char sbuf[8576];                // wsh (4*274 u) then zs[4][536]
    unsigned* wsh = (unsigned*)sbuf;
    float (*zs)[536] = (float(*)[536])sbuf;

    // stage this head-group's 4 wqb rows (pad cols 272..273 with 0)
    for (int i = tid; i < 4 * 274; i += 256) {
        int hh = i / 274, p = i - hh * 274;
        wsh[hh * 274 + p] = (p < XSU) ? wqb[(hg * 4 + hh) * XSU + p] : 0u;
    }
    __syncthreads();

    // qkm: thread tid = i*4+hh computes rows i and i+64 against head hh (uint2 loads:
    // 3x8B/iter x unroll8 = ~24 loads in flight -> max MLP at 2 waves/SIMD)
    {
        int i = tid >> 2, hh = tid & 3;
        const uint2* xr0 = (const uint2*)(xsu + (size_t)(t * NODES_PER_TREE + i) * XSU);
        const uint2* xr1 = (const uint2*)(xsu + (size_t)(t * NODES_PER_TREE + i + 64) * XSU);
        const uint2* wr  = (const uint2*)(wsh + hh * 274);
        float a0 = 0.f, a1 = 0.f;
#pragma unroll 8
        for (int j = 0; j < 133; ++j) {
            uint2 wu = wr[j];
            uint2 xa = xr0[j];
            uint2 xb = xr1[j];
            float w0 = __uint_as_float(wu.x << 16), w1 = __uint_as_float(wu.x & 0xffff0000u);
            float w2 = __uint_as_float(wu.y << 16), w3 = __uint_as_float(wu.y & 0xffff0000u);
            a0 += __uint_as_float(xa.x << 16) * w0 + __uint_as_float(xa.x & 0xffff0000u) * w1
                + __uint_as_float(xa.y << 16) * w2 + __uint_as_float(xa.y & 0xffff0000u) * w3;
            a1 += __uint_as_float(xb.x << 16) * w0 + __uint_as_float(xb.x & 0xffff0000u) * w1
                + __uint_as_float(xb.y << 16) * w2 + __uint_as_float(xb.y & 0xffff0000u) * w3;
        }
        a4[tid] = a0 * 0.125f;
        a4[tid + 256] = a1 * 0.125f;
    }
    __syncthreads();

    int hh = tid >> 6, lane = tid & 63;
    {
        float s0 = a4[lane * 4 + hh], s1 = a4[(lane + 64) * 4 + hh];
        float m = fmaxf(s0, s1);
#pragma unroll
        for (int off = 32; off > 0; off >>= 1) m = fmaxf(m, __shfl_xor(m, off, 64));
        float e0 = expf(s0 - m), e1 = expf(s1 - m);
        float sum = e0 + e1;
#pragma unroll
        for (int off = 32; off > 0; off >>= 1) sum += __shfl_xor(sum, off, 64);
        float inv = 1.0f / sum;
        a4[lane * 4 + hh] = e0 * inv;
        a4[(lane + 64) * 4 + hh] = e1 * inv;
    }
    __syncthreads();

    // z-phase: batches of 8 rows, explicit load arrays (8 global + 8 LDS loads in flight)
    {
        bool hasT = tid < 10;                 // tail uints 256..265 (j = 512..531)
        float az[4][2] = {};
        float at[4][2] = {};
        const unsigned* xt = xsu + (size_t)t * NODES_PER_TREE * XSU;
        // accumulate into registers first; zs aliases wsh so defer writes past last wsh use
        for (int i0 = 0; i0 < NODES_PER_TREE; i0 += 8) {
            unsigned u[8], u2[8];
            float4 av[8];
#pragma unroll
            for (int k = 0; k < 8; ++k) u[k] = xt[(size_t)(i0 + k) * XSU + tid];
#pragma unroll
            for (int k = 0; k < 8; ++k) u2[k] = hasT ? xt[(size_t)(i0 + k) * XSU + 256 + tid] : 0u;
#pragma unroll
            for (int k = 0; k < 8; ++k) av[k] = *(const float4*)(a4 + (i0 + k) * 4);
#pragma unroll
            for (int k = 0; k < 8; ++k) {
                float x0 = __uint_as_float(u[k] << 16);
                float x1 = __uint_as_float(u[k] & 0xffff0000u);
                float x2 = __uint_as_float(u2[k] << 16);
                float x3 = __uint_as_float(u2[k] & 0xffff0000u);
                float4 a = av[k];
                az[0][0] += a.x * x0; az[0][1] += a.x * x1;
                az[1][0] += a.y * x0; az[1][1] += a.y * x1;
                az[2][0] += a.z * x0; az[2][1] += a.z * x1;
                az[3][0] += a.w * x0; az[3][1] += a.w * x1;
                at[0][0] += a.x * x2; at[0][1] += a.x * x3;
                at[1][0] += a.y * x2; at[1][1] += a.y * x3;
                at[2][0] += a.z * x2; at[2][1] += a.z * x3;
                at[3][0] += a.w * x2; at[3][1] += a.w * x3;
            }
        }
        __syncthreads();   // all wsh reads done before zs overwrites the region
#pragma unroll
        for (int k = 0; k < 4; ++k) {
            *(float2*)(&zs[k][2 * tid]) = make_float2(az[k][0], az[k][1]);
            if (hasT) *(float2*)(&zs[k][512 + 2 * tid]) = make_float2(at[k][0], at[k][1]);
        }
    }
    __syncthreads();

    // contract: col c = hg*256 + tid; batches of 8 wvt loads, dual acc chains
    int c = hg * 256 + tid;
    const float* wp = wvt + c;
    float acc0 = 0.f, acc1 = 0.f;
    for (int j0 = 0; j0 < 528; j0 += 8) {
        float wv[8];
#pragma unroll
        for (int k = 0; k < 8; ++k) wv[k] = wp[(size_t)(j0 + k) * D_MODEL];
#pragma unroll
        for (int k = 0; k < 8; k += 2) {
            acc0 += zs[hh][j0 + k] * wv[k];
            acc1 += zs[hh][j0 + k + 1] * wv[k + 1];
        }
    }
    {
        float wv[4];
#pragma unroll
        for (int k = 0; k < 4; ++k) wv[k] = wp[(size_t)(528 + k) * D_MODEL];
#pragma unroll
        for (int k = 0; k < 4; k += 2) {
            acc0 += zs[hh][528 + k] * wv[k];
            acc1 += zs[hh][528 + k + 1] * wv[k + 1];
        }
    }
    attn_out[(size_t)t * D_MODEL + c] = acc0 + acc1;
}

// ------- MFMA split-K GEMM, BN=32 tile, fp32->bf16 hi/lo decomposition (3 MFMAs) -------
// C[128, N] = A[128, K] @ B[N, K]^T.  grid (N/32, S); K-chunk = nsb*32 per block.
__global__ __launch_bounds__(256) void gemm_mfma_sk(const float* __restrict__ A,
                                                    const float* __restrict__ B,
                                                    float* __restrict__ Cpart,
                                                    int N, int K, int nsb) {
    __shared__ __align__(16) unsigned short bhi[32 * BSTR];
    __shared__ __align__(16) unsigned short blo[32 * BSTR];
    int tid = threadIdx.x;
    int col0 = blockIdx.x * 32;
    int k0 = blockIdx.y * nsb * 32;
    float* C = Cpart + (size_t)blockIdx.y * 128 * N;

    int w = tid >> 6, l = tid & 63;
    int l15 = l & 15, l4 = l >> 4;
    int scol = tid >> 3, sk4 = (tid & 7) * 4;   // B staging: col 0..31, k-quad {0,4,...,28}

    f32x4 acc[2][2];
#pragma unroll
    for (int rt = 0; rt < 2; ++rt)
#pragma unroll
        for (int ct = 0; ct < 2; ++ct) acc[rt][ct] = (f32x4){0.f, 0.f, 0.f, 0.f};

    for (int s = 0; s < nsb; ++s) {
        int kb = k0 + s * 32;

        // ---- issue B tile load ----
        const float* bp = B + (size_t)(col0 + scol) * K + kb + sk4;
        float4 fb = *(const float4*)bp;

        // ---- issue A loads EARLY (latency hides under B split + LDS write + barrier) ----
        float4 fa[2][2];
#pragma unroll
        for (int rt = 0; rt < 2; ++rt) {
            const float* ap = A + (size_t)(32 * w + 16 * rt + l15) * K + kb + l4 * 8;
            fa[rt][0] = *(const float4*)ap;
            fa[rt][1] = *(const float4*)(ap + 4);
        }

        // ---- split B hi/lo -> LDS ----
        {
            float fe[4] = {fb.x, fb.y, fb.z, fb.w};
            unsigned hu[2], lu[2];
#pragma unroll
            for (int p = 0; p < 2; ++p) {
                unsigned u0 = __float_as_uint(fe[2 * p]);
                unsigned u1 = __float_as_uint(fe[2 * p + 1]);
                unsigned h0 = u0 & 0xffff0000u, h1 = u1 & 0xffff0000u;
                float d0 = fe[2 * p] - __uint_as_float(h0);
                float d1 = fe[2 * p + 1] - __uint_as_float(h1);
                hu[p] = h1 | (u0 >> 16);
                lu[p] = (__float_as_uint(d1) & 0xffff0000u) | (__float_as_uint(d0) >> 16);
            }
            *(uint2*)(&bhi[scol * BSTR + sk4]) = make_uint2(hu[0], hu[1]);
            *(uint2*)(&blo[scol * BSTR + sk4]) = make_uint2(lu[0], lu[1]);
        }
        __syncthreads();

        // ---- split A in regs ----
        s16x8 ah[2], al[2];
#pragma unroll
        for (int rt = 0; rt < 2; ++rt) {
            float fe[8] = {fa[rt][0].x, fa[rt][0].y, fa[rt][0].z, fa[rt][0].w,
                           fa[rt][1].x, fa[rt][1].y, fa[rt][1].z, fa[rt][1].w};
            unsigned hu[4], lu[4];
#pragma unroll
            for (int p = 0; p < 4; ++p) {
                unsigned u0 = __float_as_uint(fe[2 * p]);
                unsigned u1 = __float_as_uint(fe[2 * p + 1]);
                unsigned h0 = u0 & 0xffff0000u, h1 = u1 & 0xffff0000u;
                float d0 = fe[2 * p] - __uint_as_float(h0);
                float d1 = fe[2 * p + 1] - __uint_as_float(h1);
                hu[p] = h1 | (u0 >> 16);
                lu[p] = (__float_as_uint(d1) & 0xffff0000u) | (__float_as_uint(d0) >> 16);
            }
            PackU uh, ul;
            uh.u = make_uint4(hu[0], hu[1], hu[2], hu[3]);
            ul.u = make_uint4(lu[0], lu[1], lu[2], lu[3]);
            ah[rt] = uh.s;
            al[rt] = ul.s;
        }

        // ---- MFMA: acc += Ah*Bh + Al*Bh + Ah*Bl ----
#pragma unroll
        for (int ct = 0; ct < 2; ++ct) {
            PackU rbh, rbl;
            rbh.u = *(const uint4*)(&bhi[(16 * ct + l15) * BSTR + l4 * 8]);
            rbl.u = *(const uint4*)(&blo[(16 * ct + l15) * BSTR + l4 * 8]);
#pragma unroll
            for (int rt = 0; rt < 2; ++rt) {
                acc[rt][ct] = __builtin_amdgcn_mfma_f32_16x16x32_bf16(ah[rt], rbh.s, acc[rt][ct], 0, 0, 0);
                acc[rt][ct] = __builtin_amdgcn_mfma_f32_16x16x32_bf16(al[rt], rbh.s, acc[rt][ct], 0, 0, 0);
                acc[rt][ct] = __builtin_amdgcn_mfma_f32_16x16x32_bf16(ah[rt], rbl.s, acc[rt][ct], 0, 0, 0);
            }
        }
        __syncthreads();
    }

    // ---- epilogue: C/D layout col=l&15, row=(l>>4)*4+r ----
#pragma unroll
    for (int rt = 0; rt < 2; ++rt) {
        int row = 32 * w + 16 * rt + l4 * 4;
#pragma unroll
        for (int ct = 0; ct < 2; ++ct) {
            int col = col0 + 16 * ct + l15;
#pragma unroll
            for (int r = 0; r < 4; ++r)
                C[(size_t)(row + r) * N + col] = acc[rt][ct][r];
        }
    }
}

// ---------------- ln_r1: reduce 16 Wo-partials + bo + qvec -> r1; LN -> l1 (512 thr) ----------------
__global__ __launch_bounds__(512) void ln_r1_kernel(const float* __restrict__ po, const float* __restrict__ bo,
                             const float* __restrict__ qvec, const float* __restrict__ g,
                             const float* __restrict__ b, float* __restrict__ r1,
                             float* __restrict__ l1) {
    int t = blockIdx.x, tid = threadIdx.x;
    __shared__ float sm[18];
    float e[2];
#pragma unroll
    for (int c = 0; c < 2; ++c) {
        int j = c * 512 + tid;
        float v = bo[j] + qvec[j];
#pragma unroll
        for (int s = 0; s < 16; ++s)
            v += po[(size_t)s * NTREE * D_MODEL + (size_t)t * D_MODEL + j];
        e[c] = v;
        r1[(size_t)t * D_MODEL + j] = v;
    }
    float s = e[0] + e[1];
    float ss = e[0] * e[0] + e[1] * e[1];
    blockReduceSum2_512(s, ss, sm);
    float mu = s * (1.f / D_MODEL);
    float var = ss * (1.f / D_MODEL) - mu * mu;
    float rs = rsqrtf(var + EPS);
#pragma unroll
    for (int c = 0; c < 2; ++c) {
        int j = c * 512 + tid;
        l1[(size_t)t * D_MODEL + j] = (e[c] - mu) * rs * g[j] + b[j];
    }
}

// ---------------- gelu_reduce: h1 = gelu(sum_4 p1 + b1) ; 128x4096 elems ----------------
__global__ void gelu_reduce_kernel(const float* __restrict__ p1, const float* __restrict__ b1,
                                   float* __restrict__ h1) {
    int idx4 = (blockIdx.x * 256 + threadIdx.x) * 4;    // < 524288
    int col = idx4 & (DFF - 1);
    float4 v = *(const float4*)(b1 + col);
#pragma unroll
    for (int s = 0; s < 4; ++s) {
        float4 p = *(const float4*)(p1 + (size_t)s * NTREE * DFF + idx4);
        v.x += p.x; v.y += p.y; v.z += p.z; v.w += p.w;
    }
    v.x = gelu_exact(v.x); v.y = gelu_exact(v.y);
    v.z = gelu_exact(v.z); v.w = gelu_exact(v.w);
    *(float4*)(h1 + idx4) = v;
}

// ---------------- ln_out: reduce 16 W2-partials + b2 + r1 -> LN -> out (512 thr) ----------------
__global__ __launch_bounds__(512) void ln_out_kernel(const float* __restrict__ p2, const float* __restrict__ b2,
                              const float* __restrict__ r1, const float* __restrict__ g,
                              const float* __restrict__ b, float* __restrict__ out) {
    int t = blockIdx.x, tid = threadIdx.x;
    __shared__ float sm[18];
    float e[2];
#pragma unroll
    for (int c = 0; c < 2; ++c) {
        int j = c * 512 + tid;
        float v = b2[j] + r1[(size_t)t * D_MODEL + j];
#pragma unroll
        for (int s = 0; s < 16; ++s)
            v += p2[(size_t)s * NTREE * D_MODEL + (size_t)t * D_MODEL + j];
        e[c] = v;
    }
    float s = e[0] + e[1];
    float ss = e[0] * e[0] + e[1] * e[1];
    blockReduceSum2_512(s, ss, sm);
    float mu = s * (1.f / D_MODEL);
    float var = ss * (1.f / D_MODEL) - mu * mu;
    float rs = rsqrtf(var + EPS);
#pragma unroll
    for (int c = 0; c < 2; ++c) {
        int j = c * 512 + tid;
        out[(size_t)t * D_MODEL + j] = (e[c] - mu) * rs * g[j] + b[j];
    }
    if (t == 0 && tid < 128) out[(size_t)NTREE * D_MODEL + tid] = 0.f;
}

extern "C" void kernel_launch(void* const* d_in, const int* in_sizes, int n_in,
                              void* d_out, int out_size, void* d_ws, size_t ws_size,
                              hipStream_t stream) {
    const float* values = (const float*)d_in[0];
    const int* role     = (const int*)d_in[1];
    const int* bidx     = (const int*)d_in[2];
    const int* midx     = (const int*)d_in[3];
    const float* qvec   = (const float*)d_in[4];
    const float* Wk     = (const float*)d_in[5];
    const float* Wv     = (const float*)d_in[6];
    const float* Wo     = (const float*)d_in[7];
    const float* bo     = (const float*)d_in[8];
    const float* W1     = (const float*)d_in[9];
    const float* b1     = (const float*)d_in[10];
    const float* W2     = (const float*)d_in[11];
    const float* b2     = (const float*)d_in[12];
    const float* g_fil  = (const float*)d_in[13];
    const float* b_fil  = (const float*)d_in[14];
    const float* g_mha  = (const float*)d_in[15];
    const float* b_mha  = (const float*)d_in[16];
    const float* g_ff   = (const float*)d_in[17];
    const float* b_ff   = (const float*)d_in[18];
    const float* g_out  = (const float*)d_in[19];
    const float* b_out  = (const float*)d_in[20];

    // workspace map
    char* w = (char*)d_ws;
    int*   counts   = (int*)(w + 0);            // 128 x 128 B = 16384
    unsigned* wqb   = (unsigned*)(w + 16384);   // 17408 -> pad to 34816
    float* attn_out = (float*)(w + 34816);      // 524288 -> 559104
    float* r1       = (float*)(w + 559104);     // 524288 -> 1083392
    float* l1       = (float*)(w + 1083392);    // 524288 -> 1607680
    float* h1       = (float*)(w + 1607680);    // 2097152 -> 3704832
    float* wvt      = (float*)(w + 3704832);    // 2179072 -> 5883904
    char*  big      = w + 5883904;              // overlay region
    // phase A (prep/attn): xs (stride 544 bf16 = 1088 B/row), 16384*1088 = 17825792
    bf16*  xs = (bf16*)big;
    // phase B (GEMM partials; xs dead after attn):
    float* po = (float*)big;                    // 16*128*1024*4 = 8388608
    float* p1 = (float*)(big + 8388608);        // 4*128*4096*4  = 8388608
    float* p2 = (float*)big;                    // 16*128*1024*4 = 8388608 (po dead by then)

    float* out = (float*)d_out;  // [128*1024] fp32 ++ [128] pad mask zeros

    hipMemsetAsync(counts, 0, 16384, stream);

    // fused prep: wq (16) + Wv transpose (544) + node prep (4096) = 4656 blocks
    prep_kernel<<<4656, 256, 0, stream>>>(values, role, bidx, midx,
                                          g_fil, b_fil, g_mha, b_mha,
                                          xs, counts,
                                          qvec, Wk, wqb, Wv, wvt);

    // fused qkm + attention: flat 512 blocks (XCD-swizzled), 256 threads (R9 body)
    attn_fused_kernel<<<512, 256, 0, stream>>>((const unsigned*)xs, wqb, wvt, attn_out);

    // Wo: K=1024, 16 splits x 2 -> po [16][128][1024]; 512 blocks (2 waves/SIMD)
    gemm_mfma_sk<<<dim3(32, 16), 256, 0, stream>>>(attn_out, Wo, po, D_MODEL, D_MODEL, 2);

    ln_r1_kernel<<<NTREE, 512, 0, stream>>>(po, bo, qvec, g_ff, b_ff, r1, l1);

    // W1: K=1024, 4 splits x 256 -> p1 [4][128][4096]; 512 blocks
    gemm_mfma_sk<<<dim3(128, 4), 256, 0, stream>>>(l1, W1, p1, DFF, D_MODEL, 8);

    gelu_reduce_kernel<<<512, 256, 0, stream>>>(p1, b1, h1);

    // W2: K=4096, 16 splits x 256 -> p2 [16][128][1024]; 512 blocks
    gemm_mfma_sk<<<dim3(32, 16), 256, 0, stream>>>(h1, W2, p2, D_MODEL, DFF, 8);

    ln_out_kernel<<<NTREE, 512, 0, stream>>>(p2, b2, r1, g_out, b_out, out);
}

// Round 13
// 231.159 us; speedup vs baseline: 1.0192x; 1.0192x over previous
//
#include <hip/hip_runtime.h>
#include <hip/hip_bf16.h>

typedef __hip_bfloat16 bf16;

#define N_NODES 16384
#define D_FIL 512
#define D_IN 532
#define D_MODEL 1024
#define NHEAD 16
#define D_KEY 64
#define DFF 4096
#define NTREE 128
#define MEM_SLOTS 8
#define NODES_PER_TREE 128
#define EPS 1e-5f
#define XSE 544          // xs row stride in elements (bf16), 16B-aligned rows
#define XSU 272          // xs row stride in uints
#define CSTR 32          // counts stride in ints: 1 counter per 128B cache line
#define BSTR 40          // MFMA-GEMM B-tile LDS row stride in bf16 (80 B)

typedef float f32x4 __attribute__((ext_vector_type(4)));
typedef short s16x8 __attribute__((ext_vector_type(8)));

union PackU { uint4 u; s16x8 s; };

__device__ inline float gelu_exact(float x) {
    return 0.5f * x * (1.0f + erff(x * 0.7071067811865476f));
}

// block-wide (512 threads, 8 waves) simultaneous sum of two values
__device__ inline void blockReduceSum2_512(float& a, float& b, float* sm) {
    int tid = threadIdx.x;
    int lane = tid & 63, wid = tid >> 6;
#pragma unroll
    for (int off = 32; off > 0; off >>= 1) {
        a += __shfl_down(a, off, 64);
        b += __shfl_down(b, off, 64);
    }
    if (lane == 0) { sm[wid] = a; sm[8 + wid] = b; }
    __syncthreads();
    if (tid == 0) {
        float s0 = 0.f, s1 = 0.f;
#pragma unroll
        for (int i = 0; i < 8; ++i) { s0 += sm[i]; s1 += sm[8 + i]; }
        sm[16] = s0; sm[17] = s1;
    }
    __syncthreads();
    a = sm[16]; b = sm[17];
}

// ---------------- fused prep: wq (blocks 0..15) + Wv transpose (16..559) + node prep (560..4655) ----
__global__ __launch_bounds__(256) void prep_kernel(
        const float* __restrict__ values, const int* __restrict__ role,
        const int* __restrict__ bidx, const int* __restrict__ midx,
        const float* __restrict__ g_fil, const float* __restrict__ b_fil,
        const float* __restrict__ g_mha, const float* __restrict__ b_mha,
        bf16* __restrict__ xs, int* __restrict__ counts,
        const float* __restrict__ q, const float* __restrict__ Wk,
        unsigned* __restrict__ wqb,
        const float* __restrict__ Wv, float* __restrict__ wvt) {
    int b = blockIdx.x;
    int tid = threadIdx.x;

    if (b < 16) {
        // ---------------- wq branch ----------------
        int h = b;
        __shared__ float qs[64];
        if (tid < 64) qs[tid] = q[h * 64 + tid];
        __syncthreads();
        for (int p = tid; p < XSU; p += 256) {
            unsigned out = 0u;
            if (p < 266) {
                float a0 = 0.f, a1 = 0.f;
                int j0 = 2 * p;
#pragma unroll 8
                for (int d = 0; d < 64; ++d) {
                    const float* wr = Wk + (size_t)(h * 64 + d) * D_IN;
                    a0 += qs[d] * wr[j0];
                    a1 += qs[d] * wr[j0 + 1];
                }
                unsigned u0 = (unsigned)__bfloat16_as_ushort(__float2bfloat16(a0));
                unsigned u1 = (unsigned)__bfloat16_as_ushort(__float2bfloat16(a1));
                out = (u1 << 16) | u0;
            }
            wqb[h * XSU + p] = out;
        }
        return;
    }

    if (b < 560) {
        // ---------------- Wv transpose branch ----------------
        __shared__ float tile[32][33];
        int vb = b - 16;
        int c0 = (vb & 31) * 32, j0 = (vb >> 5) * 32;
        int tx = tid & 31, ty = tid >> 5;   // 32 x 8
#pragma unroll
        for (int r = 0; r < 4; ++r) {
            int cc = ty + r * 8;
            int j = j0 + tx;
            tile[cc][tx] = (j < D_IN) ? Wv[(size_t)(c0 + cc) * D_IN + j] : 0.f;
        }
        __syncthreads();
#pragma unroll
        for (int r = 0; r < 4; ++r) {
            int j = j0 + ty + r * 8;
            if (j < D_IN) wvt[(size_t)j * D_MODEL + c0 + tx] = tile[tx][ty + r * 8];
        }
        return;
    }

    // ---------------- node prep branch: wave-per-node ----------------
    int wave = tid >> 6;
    int l = tid & 63;
    int n = (b - 560) * 4 + wave;

    // issue the 2KB value load FIRST — nothing downstream of the atomic gates it
    const float4* vp = (const float4*)(values + (size_t)n * D_FIL + l * 8);
    float4 v0 = vp[0], v1 = vp[1];

    // issue the atomic early (lane 0 only); result consumed only at the store
    int row = 0;
    if (l == 0) {
        int slot = bidx[n] * MEM_SLOTS + midx[n];
        int pos = atomicAdd(&counts[slot * CSTR], 1);
        row = slot * NODES_PER_TREE + pos;
    }

    // ---- LN1 over 512 ----
    float s = v0.x + v0.y + v0.z + v0.w + v1.x + v1.y + v1.z + v1.w;
    float ss = v0.x * v0.x + v0.y * v0.y + v0.z * v0.z + v0.w * v0.w
             + v1.x * v1.x + v1.y * v1.y + v1.z * v1.z + v1.w * v1.w;
#pragma unroll
    for (int m = 1; m < 64; m <<= 1) {
        s += __shfl_xor(s, m, 64);
        ss += __shfl_xor(ss, m, 64);
    }
    float mu = s * (1.f / D_FIL);
    float var = ss * (1.f / D_FIL) - mu * mu;
    float rs = rsqrtf(var + EPS);

    const float4* gf = (const float4*)(g_fil + l * 8);
    const float4* bf = (const float4*)(b_fil + l * 8);
    float4 gf0 = gf[0], gf1 = gf[1], bf0 = bf[0], bf1 = bf[1];
    float y[8];
    y[0] = (v0.x - mu) * rs * gf0.x + bf0.x;
    y[1] = (v0.y - mu) * rs * gf0.y + bf0.y;
    y[2] = (v0.z - mu) * rs * gf0.z + bf0.z;
    y[3] = (v0.w - mu) * rs * gf0.w + bf0.w;
    y[4] = (v1.x - mu) * rs * gf1.x + bf1.x;
    y[5] = (v1.y - mu) * rs * gf1.y + bf1.y;
    y[6] = (v1.z - mu) * rs * gf1.z + bf1.z;
    y[7] = (v1.w - mu) * rs * gf1.w + bf1.w;

    // ---- tpd analytic stats ----
    int r = role[n];                 // r >= 1
    int cm = 31 - __clz(r);          // highest set bit, 0..19
    float s_t = 2.f * (float)(__popc(r) - 1) - (float)cm;
    float ss_t = (float)cm;

    // ---- LN2 over 532 ----
    float s2 = y[0] + y[1] + y[2] + y[3] + y[4] + y[5] + y[6] + y[7];
    float ss2 = y[0] * y[0] + y[1] * y[1] + y[2] * y[2] + y[3] * y[3]
              + y[4] * y[4] + y[5] * y[5] + y[6] * y[6] + y[7] * y[7];
#pragma unroll
    for (int m = 1; m < 64; m <<= 1) {
        s2 += __shfl_xor(s2, m, 64);
        ss2 += __shfl_xor(ss2, m, 64);
    }
    s2 += s_t; ss2 += ss_t;
    float mu2 = s2 * (1.f / D_IN);
    float var2 = ss2 * (1.f / D_IN) - mu2 * mu2;
    float rs2 = rsqrtf(var2 + EPS);

    const float4* gm = (const float4*)(g_mha + l * 8);
    const float4* bm = (const float4*)(b_mha + l * 8);
    float4 gm0 = gm[0], gm1 = gm[1], bm0 = bm[0], bm1 = bm[1];
    float x[8];
    x[0] = (y[0] - mu2) * rs2 * gm0.x + bm0.x;
    x[1] = (y[1] - mu2) * rs2 * gm0.y + bm0.y;
    x[2] = (y[2] - mu2) * rs2 * gm0.z + bm0.z;
    x[3] = (y[3] - mu2) * rs2 * gm0.w + bm0.w;
    x[4] = (y[4] - mu2) * rs2 * gm1.x + bm1.x;
    x[5] = (y[5] - mu2) * rs2 * gm1.y + bm1.y;
    x[6] = (y[6] - mu2) * rs2 * gm1.z + bm1.z;
    x[7] = (y[7] - mu2) * rs2 * gm1.w + bm1.w;

    // broadcast row AFTER the compute so the atomic round-trip hid under LN1/LN2
    row = __shfl(row, 0, 64);

    // one uint4 store: 8 bf16 = 16 B, rows 16B-aligned (stride 1088 B)
    {
        unsigned us[8];
#pragma unroll
        for (int k = 0; k < 8; ++k)
            us[k] = (unsigned)__bfloat16_as_ushort(__float2bfloat16(x[k]));
        uint4 pk = make_uint4((us[1] << 16) | us[0], (us[3] << 16) | us[2],
                              (us[5] << 16) | us[4], (us[7] << 16) | us[6]);
        *(uint4*)((char*)xs + (size_t)row * (XSE * 2) + 16 * l) = pk;
    }

    // tail j = 512..531, zero-pad 532..543
    if (l < 20) {
        int bit = (r >> l) & 1;
        float tpd = (l < cm) ? (bit ? 1.f : -1.f) : 0.f;
        float x2 = (tpd - mu2) * rs2 * g_mha[512 + l] + b_mha[512 + l];
        xs[(size_t)row * XSE + 512 + l] = __float2bfloat16(x2);
    } else if (l < 26) {
        ((unsigned*)xs)[(size_t)row * XSU + 266 + (l - 20)] = 0u;
    }
}

// ------- fused qkm + attention (R9-exact body: uint2 qkm for max MLP) + XCD swizzle -------
// flat grid 512: xcd = f&7, hg = (f>>3)&3, t = (f>>5)*8 + xcd  (bijective).
// A tree's 4 head-group blocks share f&7 -> same XCD -> xs slab HBM-fetched once.
__global__ __launch_bounds__(256) void attn_fused_kernel(const unsigned* __restrict__ xsu,
                                                         const unsigned* __restrict__ wqb,
                                                         const float* __restrict__ wvt,
                                                         float* __restrict__ attn_out) {
    int f = blockIdx.x;
    int xcd = f & 7;
    int hg = (f >> 3) & 3;
    int t = (f >> 5) * 8 + xcd;
    int tid = threadIdx.x;
    __shared__ __align__(16) float a4[NODES_PER_TREE * 4];   // [i*4 + hh]
    __shared__ __align__(16) char sbuf[8576];                // wsh (4*274 u) then zs[4][536]
    unsigned* wsh = (unsigned*)sbuf;
    float (*zs)[536] = (float(*)[536])sbuf;

    // stage this head-group's 4 wqb rows (pad cols 272..273 with 0)
    for (int i = tid; i < 4 * 274; i += 256) {
        int hh = i / 274, p = i - hh * 274;
        wsh[hh * 274 + p] = (p < XSU) ? wqb[(hg * 4 + hh) * XSU + p] : 0u;
    }
    __syncthreads();

    // qkm: thread tid = i*4+hh computes rows i and i+64 against head hh (uint2 loads:
    // 3x8B/iter x unroll8 = ~24 loads in flight -> max MLP at 2 waves/SIMD)
    {
        int i = tid >> 2, hh = tid & 3;
        const uint2* xr0 = (const uint2*)(xsu + (size_t)(t * NODES_PER_TREE + i) * XSU);
        const uint2* xr1 = (const uint2*)(xsu + (size_t)(t * NODES_PER_TREE + i + 64) * XSU);
        const uint2* wr  = (const uint2*)(wsh + hh * 274);
        float a0 = 0.f, a1 = 0.f;
#pragma unroll 8
        for (int j = 0; j < 133; ++j) {
            uint2 wu = wr[j];
            uint2 xa = xr0[j];
            uint2 xb = xr1[j];
            float w0 = __uint_as_float(wu.x << 16), w1 = __uint_as_float(wu.x & 0xffff0000u);
            float w2 = __uint_as_float(wu.y << 16), w3 = __uint_as_float(wu.y & 0xffff0000u);
            a0 += __uint_as_float(xa.x << 16) * w0 + __uint_as_float(xa.x & 0xffff0000u) * w1
                + __uint_as_float(xa.y << 16) * w2 + __uint_as_float(xa.y & 0xffff0000u) * w3;
            a1 += __uint_as_float(xb.x << 16) * w0 + __uint_as_float(xb.x & 0xffff0000u) * w1
                + __uint_as_float(xb.y << 16) * w2 + __uint_as_float(xb.y & 0xffff0000u) * w3;
        }
        a4[tid] = a0 * 0.125f;
        a4[tid + 256] = a1 * 0.125f;
    }
    __syncthreads();

    int hh = tid >> 6, lane = tid & 63;
    {
        float s0 = a4[lane * 4 + hh], s1 = a4[(lane + 64) * 4 + hh];
        float m = fmaxf(s0, s1);
#pragma unroll
        for (int off = 32; off > 0; off >>= 1) m = fmaxf(m, __shfl_xor(m, off, 64));
        float e0 = expf(s0 - m), e1 = expf(s1 - m);
        float sum = e0 + e1;
#pragma unroll
        for (int off = 32; off > 0; off >>= 1) sum += __shfl_xor(sum, off, 64);
        float inv = 1.0f / sum;
        a4[lane * 4 + hh] = e0 * inv;
        a4[(lane + 64) * 4 + hh] = e1 * inv;
    }
    __syncthreads();

    // z-phase: batches of 8 rows, explicit load arrays (8 global + 8 LDS loads in flight)
    {
        bool hasT = tid < 10;                 // tail uints 256..265 (j = 512..531)
        float az[4][2] = {};
        float at[4][2] = {};
        const unsigned* xt = xsu + (size_t)t * NODES_PER_TREE * XSU;
        // accumulate into registers first; zs aliases wsh so defer writes past last wsh use
        for (int i0 = 0; i0 < NODES_PER_TREE; i0 += 8) {
            unsigned u[8], u2[8];
            float4 av[8];
#pragma unroll
            for (int k = 0; k < 8; ++k) u[k] = xt[(size_t)(i0 + k) * XSU + tid];
#pragma unroll
            for (int k = 0; k < 8; ++k) u2[k] = hasT ? xt[(size_t)(i0 + k) * XSU + 256 + tid] : 0u;
#pragma unroll
            for (int k = 0; k < 8; ++k) av[k] = *(const float4*)(a4 + (i0 + k) * 4);
#pragma unroll
            for (int k = 0; k < 8; ++k) {
                float x0 = __uint_as_float(u[k] << 16);
                float x1 = __uint_as_float(u[k] & 0xffff0000u);
                float x2 = __uint_as_float(u2[k] << 16);
                float x3 = __uint_as_float(u2[k] & 0xffff0000u);
                float4 a = av[k];
                az[0][0] += a.x * x0; az[0][1] += a.x * x1;
                az[1][0] += a.y * x0; az[1][1] += a.y * x1;
                az[2][0] += a.z * x0; az[2][1] += a.z * x1;
                az[3][0] += a.w * x0; az[3][1] += a.w * x1;
                at[0][0] += a.x * x2; at[0][1] += a.x * x3;
                at[1][0] += a.y * x2; at[1][1] += a.y * x3;
                at[2][0] += a.z * x2; at[2][1] += a.z * x3;
                at[3][0] += a.w * x2; at[3][1] += a.w * x3;
            }
        }
        __syncthreads();   // all wsh reads done before zs overwrites the region
#pragma unroll
        for (int k = 0; k < 4; ++k) {
            *(float2*)(&zs[k][2 * tid]) = make_float2(az[k][0], az[k][1]);
            if (hasT) *(float2*)(&zs[k][512 + 2 * tid]) = make_float2(at[k][0], at[k][1]);
        }
    }
    __syncthreads();

    // contract: col c = hg*256 + tid; batches of 8 wvt loads, dual acc chains
    int c = hg * 256 + tid;
    const float* wp = wvt + c;
    float acc0 = 0.f, acc1 = 0.f;
    for (int j0 = 0; j0 < 528; j0 += 8) {
        float wv[8];
#pragma unroll
        for (int k = 0; k < 8; ++k) wv[k] = wp[(size_t)(j0 + k) * D_MODEL];
#pragma unroll
        for (int k = 0; k < 8; k += 2) {
            acc0 += zs[hh][j0 + k] * wv[k];
            acc1 += zs[hh][j0 + k + 1] * wv[k + 1];
        }
    }
    {
        float wv[4];
#pragma unroll
        for (int k = 0; k < 4; ++k) wv[k] = wp[(size_t)(528 + k) * D_MODEL];
#pragma unroll
        for (int k = 0; k < 4; k += 2) {
            acc0 += zs[hh][528 + k] * wv[k];
            acc1 += zs[hh][528 + k + 1] * wv[k + 1];
        }
    }
    attn_out[(size_t)t * D_MODEL + c] = acc0 + acc1;
}

// ------- MFMA split-K GEMM, BN=32 tile, fp32->bf16 hi/lo decomposition (3 MFMAs) -------
// C[128, N] = A[128, K] @ B[N, K]^T.  grid (N/32, S); K-chunk = nsb*32 per block.
__global__ __launch_bounds__(256) void gemm_mfma_sk(const float* __restrict__ A,
                                                    const float* __restrict__ B,
                                                    float* __restrict__ Cpart,
                                                    int N, int K, int nsb) {
    __shared__ __align__(16) unsigned short bhi[32 * BSTR];
    __shared__ __align__(16) unsigned short blo[32 * BSTR];
    int tid = threadIdx.x;
    int col0 = blockIdx.x * 32;
    int k0 = blockIdx.y * nsb * 32;
    float* C = Cpart + (size_t)blockIdx.y * 128 * N;

    int w = tid >> 6, l = tid & 63;
    int l15 = l & 15, l4 = l >> 4;
    int scol = tid >> 3, sk4 = (tid & 7) * 4;   // B staging: col 0..31, k-quad {0,4,...,28}

    f32x4 acc[2][2];
#pragma unroll
    for (int rt = 0; rt < 2; ++rt)
#pragma unroll
        for (int ct = 0; ct < 2; ++ct) acc[rt][ct] = (f32x4){0.f, 0.f, 0.f, 0.f};

    for (int s = 0; s < nsb; ++s) {
        int kb = k0 + s * 32;

        // ---- issue B tile load ----
        const float* bp = B + (size_t)(col0 + scol) * K + kb + sk4;
        float4 fb = *(const float4*)bp;

        // ---- issue A loads EARLY (latency hides under B split + LDS write + barrier) ----
        float4 fa[2][2];
#pragma unroll
        for (int rt = 0; rt < 2; ++rt) {
            const float* ap = A + (size_t)(32 * w + 16 * rt + l15) * K + kb + l4 * 8;
            fa[rt][0] = *(const float4*)ap;
            fa[rt][1] = *(const float4*)(ap + 4);
        }

        // ---- split B hi/lo -> LDS ----
        {
            float fe[4] = {fb.x, fb.y, fb.z, fb.w};
            unsigned hu[2], lu[2];
#pragma unroll
            for (int p = 0; p < 2; ++p) {
                unsigned u0 = __float_as_uint(fe[2 * p]);
                unsigned u1 = __float_as_uint(fe[2 * p + 1]);
                unsigned h0 = u0 & 0xffff0000u, h1 = u1 & 0xffff0000u;
                float d0 = fe[2 * p] - __uint_as_float(h0);
                float d1 = fe[2 * p + 1] - __uint_as_float(h1);
                hu[p] = h1 | (u0 >> 16);
                lu[p] = (__float_as_uint(d1) & 0xffff0000u) | (__float_as_uint(d0) >> 16);
            }
            *(uint2*)(&bhi[scol * BSTR + sk4]) = make_uint2(hu[0], hu[1]);
            *(uint2*)(&blo[scol * BSTR + sk4]) = make_uint2(lu[0], lu[1]);
        }
        __syncthreads();

        // ---- split A in regs ----
        s16x8 ah[2], al[2];
#pragma unroll
        for (int rt = 0; rt < 2; ++rt) {
            float fe[8] = {fa[rt][0].x, fa[rt][0].y, fa[rt][0].z, fa[rt][0].w,
                           fa[rt][1].x, fa[rt][1].y, fa[rt][1].z, fa[rt][1].w};
            unsigned hu[4], lu[4];
#pragma unroll
            for (int p = 0; p < 4; ++p) {
                unsigned u0 = __float_as_uint(fe[2 * p]);
                unsigned u1 = __float_as_uint(fe[2 * p + 1]);
                unsigned h0 = u0 & 0xffff0000u, h1 = u1 & 0xffff0000u;
                float d0 = fe[2 * p] - __uint_as_float(h0);
                float d1 = fe[2 * p + 1] - __uint_as_float(h1);
                hu[p] = h1 | (u0 >> 16);
                lu[p] = (__float_as_uint(d1) & 0xffff0000u) | (__float_as_uint(d0) >> 16);
            }
            PackU uh, ul;
            uh.u = make_uint4(hu[0], hu[1], hu[2], hu[3]);
            ul.u = make_uint4(lu[0], lu[1], lu[2], lu[3]);
            ah[rt] = uh.s;
            al[rt] = ul.s;
        }

        // ---- MFMA: acc += Ah*Bh + Al*Bh + Ah*Bl ----
#pragma unroll
        for (int ct = 0; ct < 2; ++ct) {
            PackU rbh, rbl;
            rbh.u = *(const uint4*)(&bhi[(16 * ct + l15) * BSTR + l4 * 8]);
            rbl.u = *(const uint4*)(&blo[(16 * ct + l15) * BSTR + l4 * 8]);
#pragma unroll
            for (int rt = 0; rt < 2; ++rt) {
                acc[rt][ct] = __builtin_amdgcn_mfma_f32_16x16x32_bf16(ah[rt], rbh.s, acc[rt][ct], 0, 0, 0);
                acc[rt][ct] = __builtin_amdgcn_mfma_f32_16x16x32_bf16(al[rt], rbh.s, acc[rt][ct], 0, 0, 0);
                acc[rt][ct] = __builtin_amdgcn_mfma_f32_16x16x32_bf16(ah[rt], rbl.s, acc[rt][ct], 0, 0, 0);
            }
        }
        __syncthreads();
    }

    // ---- epilogue: C/D layout col=l&15, row=(l>>4)*4+r ----
#pragma unroll
    for (int rt = 0; rt < 2; ++rt) {
        int row = 32 * w + 16 * rt + l4 * 4;
#pragma unroll
        for (int ct = 0; ct < 2; ++ct) {
            int col = col0 + 16 * ct + l15;
#pragma unroll
            for (int r = 0; r < 4; ++r)
                C[(size_t)(row + r) * N + col] = acc[rt][ct][r];
        }
    }
}

// ---------------- ln_r1: reduce 8 Wo-partials + bo + qvec -> r1; LN -> l1 (512 thr) ----------------
__global__ __launch_bounds__(512) void ln_r1_kernel(const float* __restrict__ po, const float* __restrict__ bo,
                             const float* __restrict__ qvec, const float* __restrict__ g,
                             const float* __restrict__ b, float* __restrict__ r1,
                             float* __restrict__ l1) {
    int t = blockIdx.x, tid = threadIdx.x;
    __shared__ float sm[18];
    float e[2];
#pragma unroll
    for (int c = 0; c < 2; ++c) {
        int j = c * 512 + tid;
        float v = bo[j] + qvec[j];
#pragma unroll
        for (int s = 0; s < 8; ++s)
            v += po[(size_t)s * NTREE * D_MODEL + (size_t)t * D_MODEL + j];
        e[c] = v;
        r1[(size_t)t * D_MODEL + j] = v;
    }
    float s = e[0] + e[1];
    float ss = e[0] * e[0] + e[1] * e[1];
    blockReduceSum2_512(s, ss, sm);
    float mu = s * (1.f / D_MODEL);
    float var = ss * (1.f / D_MODEL) - mu * mu;
    float rs = rsqrtf(var + EPS);
#pragma unroll
    for (int c = 0; c < 2; ++c) {
        int j = c * 512 + tid;
        l1[(size_t)t * D_MODEL + j] = (e[c] - mu) * rs * g[j] + b[j];
    }
}

// ---------------- gelu_reduce: h1 = gelu(sum_4 p1 + b1) ; 128x4096 elems ----------------
__global__ void gelu_reduce_kernel(const float* __restrict__ p1, const float* __restrict__ b1,
                                   float* __restrict__ h1) {
    int idx4 = (blockIdx.x * 256 + threadIdx.x) * 4;    // < 524288
    int col = idx4 & (DFF - 1);
    float4 v = *(const float4*)(b1 + col);
#pragma unroll
    for (int s = 0; s < 4; ++s) {
        float4 p = *(const float4*)(p1 + (size_t)s * NTREE * DFF + idx4);
        v.x += p.x; v.y += p.y; v.z += p.z; v.w += p.w;
    }
    v.x = gelu_exact(v.x); v.y = gelu_exact(v.y);
    v.z = gelu_exact(v.z); v.w = gelu_exact(v.w);
    *(float4*)(h1 + idx4) = v;
}

// ---------------- ln_out: reduce 16 W2-partials + b2 + r1 -> LN -> out (512 thr) ----------------
__global__ __launch_bounds__(512) void ln_out_kernel(const float* __restrict__ p2, const float* __restrict__ b2,
                              const float* __restrict__ r1, const float* __restrict__ g,
                              const float* __restrict__ b, float* __restrict__ out) {
    int t = blockIdx.x, tid = threadIdx.x;
    __shared__ float sm[18];
    float e[2];
#pragma unroll
    for (int c = 0; c < 2; ++c) {
        int j = c * 512 + tid;
        float v = b2[j] + r1[(size_t)t * D_MODEL + j];
#pragma unroll
        for (int s = 0; s < 16; ++s)
            v += p2[(size_t)s * NTREE * D_MODEL + (size_t)t * D_MODEL + j];
        e[c] = v;
    }
    float s = e[0] + e[1];
    float ss = e[0] * e[0] + e[1] * e[1];
    blockReduceSum2_512(s, ss, sm);
    float mu = s * (1.f / D_MODEL);
    float var = ss * (1.f / D_MODEL) - mu * mu;
    float rs = rsqrtf(var + EPS);
#pragma unroll
    for (int c = 0; c < 2; ++c) {
        int j = c * 512 + tid;
        out[(size_t)t * D_MODEL + j] = (e[c] - mu) * rs * g[j] + b[j];
    }
    if (t == 0 && tid < 128) out[(size_t)NTREE * D_MODEL + tid] = 0.f;
}

extern "C" void kernel_launch(void* const* d_in, const int* in_sizes, int n_in,
                              void* d_out, int out_size, void* d_ws, size_t ws_size,
                              hipStream_t stream) {
    const float* values = (const float*)d_in[0];
    const int* role     = (const int*)d_in[1];
    const int* bidx     = (const int*)d_in[2];
    const int* midx     = (const int*)d_in[3];
    const float* qvec   = (const float*)d_in[4];
    const float* Wk     = (const float*)d_in[5];
    const float* Wv     = (const float*)d_in[6];
    const float* Wo     = (const float*)d_in[7];
    const float* bo     = (const float*)d_in[8];
    const float* W1     = (const float*)d_in[9];
    const float* b1     = (const float*)d_in[10];
    const float* W2     = (const float*)d_in[11];
    const float* b2     = (const float*)d_in[12];
    const float* g_fil  = (const float*)d_in[13];
    const float* b_fil  = (const float*)d_in[14];
    const float* g_mha  = (const float*)d_in[15];
    const float* b_mha  = (const float*)d_in[16];
    const float* g_ff   = (const float*)d_in[17];
    const float* b_ff   = (const float*)d_in[18];
    const float* g_out  = (const float*)d_in[19];
    const float* b_out  = (const float*)d_in[20];

    // workspace map
    char* w = (char*)d_ws;
    int*   counts   = (int*)(w + 0);            // 128 x 128 B = 16384
    unsigned* wqb   = (unsigned*)(w + 16384);   // 17408 -> pad to 34816
    float* attn_out = (float*)(w + 34816);      // 524288 -> 559104
    float* r1       = (float*)(w + 559104);     // 524288 -> 1083392
    float* l1       = (float*)(w + 1083392);    // 524288 -> 1607680
    float* h1       = (float*)(w + 1607680);    // 2097152 -> 3704832
    float* wvt      = (float*)(w + 3704832);    // 2179072 -> 5883904
    char*  big      = w + 5883904;              // overlay region
    // phase A (prep/attn): xs (stride 544 bf16 = 1088 B/row), 16384*1088 = 17825792
    bf16*  xs = (bf16*)big;
    // phase B (GEMM partials; xs dead after attn):
    float* po = (float*)big;                    // 8*128*1024*4  = 4194304
    float* p1 = (float*)(big + 4194304);        // 4*128*4096*4  = 8388608
    float* p2 = (float*)big;                    // 16*128*1024*4 = 8388608 (po dead by then)

    float* out = (float*)d_out;  // [128*1024] fp32 ++ [128] pad mask zeros

    hipMemsetAsync(counts, 0, 16384, stream);

    // fused prep: wq (16) + Wv transpose (544) + node prep (4096) = 4656 blocks
    prep_kernel<<<4656, 256, 0, stream>>>(values, role, bidx, midx,
                                          g_fil, b_fil, g_mha, b_mha,
                                          xs, counts,
                                          qvec, Wk, wqb, Wv, wvt);

    // fused qkm + attention: flat 512 blocks (XCD-swizzled), 256 threads (R9 body)
    attn_fused_kernel<<<512, 256, 0, stream>>>((const unsigned*)xs, wqb, wvt, attn_out);

    // Wo: K=1024, 8 splits x nsb=4 -> po [8][128][1024]; 256 blocks (R9 config)
    gemm_mfma_sk<<<dim3(32, 8), 256, 0, stream>>>(attn_out, Wo, po, D_MODEL, D_MODEL, 4);

    ln_r1_kernel<<<NTREE, 512, 0, stream>>>(po, bo, qvec, g_ff, b_ff, r1, l1);

    // W1: K=1024, 4 splits x 256 -> p1 [4][128][4096]; 512 blocks
    gemm_mfma_sk<<<dim3(128, 4), 256, 0, stream>>>(l1, W1, p1, DFF, D_MODEL, 8);

    gelu_reduce_kernel<<<512, 256, 0, stream>>>(p1, b1, h1);

    // W2: K=4096, 16 splits x 256 -> p2 [16][128][1024]; 512 blocks
    gemm_mfma_sk<<<dim3(32, 16), 256, 0, stream>>>(h1, W2, p2, D_MODEL, DFF, 8);

    ln_out_kernel<<<NTREE, 512, 0, stream>>>(p2, b2, r1, g_out, b_out, out);
}